// Round 1
// baseline (396.121 us; speedup 1.0000x reference)
//
#include <hip/hip_runtime.h>

#define EPS 1e-5f
#define PROJ_EPS 1e-5f
#define MAX_TANH_ARG 15.0f

typedef __bf16 bf16x8 __attribute__((ext_vector_type(8)));
typedef float f32x4 __attribute__((ext_vector_type(4)));
typedef float f32x2 __attribute__((ext_vector_type(2)));

__device__ __forceinline__ unsigned short f2bf(float f) {
  unsigned u = __builtin_bit_cast(unsigned, f);
  u += 0x7fffu + ((u >> 16) & 1u);   // round-to-nearest-even
  return (unsigned short)(u >> 16);
}

union BF8 {
  unsigned short u[8];
  bf16x8 v;
  uint4 q;
};

// ---------------------------------------------------------------------------
// prep: W[layer][k][n] -> bf16 MFMA B-frag order.
// ---------------------------------------------------------------------------
__global__ __launch_bounds__(256) void prep_kernel(
    const float* __restrict__ W, unsigned short* __restrict__ wpack) {
  const int tid = blockIdx.x * 256 + threadIdx.x;
  if (tid >= 4096) return;
  const int l = tid & 63;
  const int s = (tid >> 6) & 3;
  const int tt = (tid >> 8) & 7;
  const int layer = tid >> 11;
  const int q2 = l >> 4;
  const int n = tt * 16 + (l & 15);
  unsigned short* dst = wpack + ((size_t)((layer * 32 + tt * 4 + s) * 64 + l)) * 8;
  const float* src = W + (size_t)layer * 16384;
#pragma unroll
  for (int j = 0; j < 8; ++j) {
    const int k = s * 32 + q2 * 8 + j;
    dst[j] = f2bf(src[(size_t)k * 128 + n]);
  }
}

// ---------------------------------------------------------------------------
// gemm0: msg1 planes = mask^2 * (node_repr @ W0); also packs this tile's
// edges (u16 id | f16 w) into ws (coalesced, overlapped with MFMA).
// No __syncthreads: every wave stages/reads/writes only its own 16 rows.
// ---------------------------------------------------------------------------
__global__ __launch_bounds__(256) void gemm0_kernel(
    const float* __restrict__ xf, const float* __restrict__ mask,
    const unsigned short* __restrict__ wpack, unsigned short* __restrict__ msg,
    const int* __restrict__ adj, const float* __restrict__ wgt,
    unsigned* __restrict__ edges, int nedge, int N, int planeBytes) {
  __shared__ unsigned short tile[64][136];
  const int t = threadIdx.x;
  const int lane = t & 63;
  const int wv = t >> 6;
  const int m = lane & 15;
  const int quad = lane >> 4;
  const int base = blockIdx.x * 64;
  const int wbase = base + wv * 16;

  // Pack this tile's 2048 edges (8 coalesced iterations).
#pragma unroll
  for (int i = 0; i < 8; ++i) {
    const int ge = base * 32 + i * 256 + t;
    if (ge < nedge) {
      const unsigned id = (unsigned)adj[ge] & 0xffffu;
      const unsigned short h = __builtin_bit_cast(unsigned short, (_Float16)wgt[ge]);
      edges[ge] = id | ((unsigned)h << 16);
    }
  }

  {  // coalesced fp32 load -> bf16 stage into own wave's 16 tile rows
    const int r = lane >> 2;
    const int c = (lane & 3) * 32;
    const int gr = wbase + r;
    const int grc = gr < N ? gr : N - 1;
    const float4* src = (const float4*)(xf + (size_t)grc * 128 + c);
    unsigned short* drow = &tile[wv * 16 + r][c];
#pragma unroll
    for (int i = 0; i < 8; ++i) {
      const float4 p = src[i];
      drow[i * 4 + 0] = f2bf(p.x);
      drow[i * 4 + 1] = f2bf(p.y);
      drow[i * 4 + 2] = f2bf(p.z);
      drow[i * 4 + 3] = f2bf(p.w);
    }
  }

  f32x4 acc[8];
#pragma unroll
  for (int tt = 0; tt < 8; ++tt) acc[tt] = (f32x4){0.f, 0.f, 0.f, 0.f};
#pragma unroll
  for (int sk = 0; sk < 4; ++sk) {
    BF8 a;
    a.q = *(const uint4*)&tile[wv * 16 + m][sk * 32 + quad * 8];
#pragma unroll
    for (int tt = 0; tt < 8; ++tt) {
      BF8 b;
      b.q = *(const uint4*)(wpack + (size_t)((tt * 4 + sk) * 64 + lane) * 8);
      acc[tt] = __builtin_amdgcn_mfma_f32_16x16x32_bf16(a.v, b.v, acc[tt], 0, 0, 0);
    }
  }

  float sc[4];
#pragma unroll
  for (int r = 0; r < 4; ++r) {
    int rr = wbase + quad * 4 + r;
    rr = rr < N ? rr : N - 1;
    const float s = mask[rr];
    sc[r] = s * s;
  }
#pragma unroll
  for (int tt = 0; tt < 8; ++tt) {
    const int c = tt * 16 + m;
#pragma unroll
    for (int r = 0; r < 4; ++r)
      tile[wv * 16 + quad * 4 + r][c] = f2bf(acc[tt][r] * sc[r]);
  }
  const int r16 = lane >> 2;
  const int sub2 = lane & 3;
  const int grow = wbase + r16;
  if (grow < N) {
#pragma unroll
    for (int p = 0; p < 4; ++p) {
      *(uint4*)((char*)msg + (size_t)p * planeBytes + (size_t)grow * 64 + sub2 * 16) =
          *(const uint4*)((const char*)&tile[wv * 16 + r16][0] + p * 64 + sub2 * 16);
    }
  }
}

// ---------------------------------------------------------------------------
// agg_gemm1: fused gather(all 4 planes) + gemm1 per 64-node tile.
// - Zero __syncthreads: wave w gathers rows [w*16, w*16+16) and later feeds
//   exactly those rows to its own MFMAs (in-wave LDS ordering only).
// - Phase-rotated plane order (pstart = blockIdx&3 ~= XCD id&3) keeps each
//   XCD's L2 on a single 3.2MB plane at any time (2 XCDs/plane, same
//   affinity as the old per-plane gather grid).
// - One 128-deep rolling gather pipeline (16 uint4 in flight) spanning all
//   4 planes; per-plane epilogue packs relu(c1) bf16 into the LDS A-tile
//   and accumulates ||c1||^2 / ||relu(c1)||^2 in registers.
// ---------------------------------------------------------------------------
__global__ __launch_bounds__(256, 3) void agg_gemm1_kernel(
    const unsigned short* __restrict__ msg, const unsigned* __restrict__ edges,
    const float* __restrict__ mask, const unsigned short* __restrict__ wpack2,
    unsigned short* __restrict__ msg2, int N, int planeBytes) {
  __shared__ unsigned ep[64 * 36];
  __shared__ unsigned short tile[64][136];
  __shared__ float sAll[64];
  __shared__ float sRel[64];
  const int t = threadIdx.x;
  const int lane = t & 63;
  const int wv = t >> 6;
  const int nbase = blockIdx.x * 64;
  const int wrow0 = wv * 16;
  const int pstart = blockIdx.x & 3;

  // per-wave edge stage (16 rows x 32 words), fully coalesced
#pragma unroll
  for (int i = 0; i < 2; ++i) {
    const int idx = lane + i * 64;
    const int row = idx >> 3;
    const int qd = idx & 7;
    const int gn = nbase + wrow0 + row;
    uint4 v = {0u, 0u, 0u, 0u};
    if (gn < N) v = *(const uint4*)(edges + (size_t)gn * 32 + qd * 4);
    *(uint4*)&ep[(wrow0 + row) * 36 + qd * 4] = v;
  }

  const int node = lane >> 2;
  const int sub = lane & 3;
  const int suboff = sub * 16;
  const unsigned* mp = ep + (wrow0 + node) * 36;
  unsigned ew[32];
#pragma unroll
  for (int i = 0; i < 8; ++i) *(uint4*)&ew[4 * i] = *(const uint4*)(mp + 4 * i);

  const char* pb[4];
#pragma unroll
  for (int ph = 0; ph < 4; ++ph)
    pb[ph] = (const char*)msg + (size_t)((pstart + ph) & 3) * planeBytes;

  f32x2 acc[4];
#pragma unroll
  for (int d = 0; d < 4; ++d) acc[d] = (f32x2){0.f, 0.f};
  float s_all = 0.f, s_rel = 0.f;

  uint4 q[16];
#pragma unroll
  for (int e = 0; e < 16; ++e)
    q[e] = *(const uint4*)(pb[e >> 5] + ((ew[e & 31] & 0xffffu) * 64 + suboff));

#pragma unroll
  for (int e = 0; e < 128; ++e) {
    const int k = e & 31;
    const float w = (float)__builtin_bit_cast(_Float16, (unsigned short)(ew[k] >> 16));
    const f32x2 w2 = {w, w};
    const uint4 qq = q[e & 15];
    const int en = e + 16;
    if (en < 128)
      q[e & 15] = *(const uint4*)(pb[en >> 5] + ((ew[en & 31] & 0xffffu) * 64 + suboff));
#pragma unroll
    for (int d = 0; d < 4; ++d) {
      const unsigned qd = (&qq.x)[d];
      f32x2 v2;
      v2.x = __builtin_bit_cast(float, qd << 16);
      v2.y = __builtin_bit_cast(float, qd & 0xffff0000u);
      acc[d] = __builtin_elementwise_fma(v2, w2, acc[d]);
    }
    if (k == 31) {  // plane finished: norms + relu + bf16 pack into A-tile
      const int p = (pstart + (e >> 5)) & 3;
      uint4 pk4;
      unsigned* pw = &pk4.x;
#pragma unroll
      for (int d = 0; d < 4; ++d) {
        s_all = fmaf(acc[d].x, acc[d].x, s_all);
        s_all = fmaf(acc[d].y, acc[d].y, s_all);
        const float r0 = fmaxf(acc[d].x, 0.f);
        const float r1 = fmaxf(acc[d].y, 0.f);
        s_rel = fmaf(r0, r0, s_rel);
        s_rel = fmaf(r1, r1, s_rel);
        pw[d] = (unsigned)f2bf(r0) | ((unsigned)f2bf(r1) << 16);
        acc[d] = (f32x2){0.f, 0.f};
      }
      *(uint4*)&tile[wrow0 + node][p * 32 + sub * 8] = pk4;
    }
  }

  s_all += __shfl_xor(s_all, 1);
  s_all += __shfl_xor(s_all, 2);
  s_rel += __shfl_xor(s_rel, 1);
  s_rel += __shfl_xor(s_rel, 2);
  if (sub == 0) {
    sAll[wrow0 + node] = s_all;
    sRel[wrow0 + node] = s_rel;
  }

  // gemm phase: A = relu(c1) bf16 from own-wave LDS rows, B = W1 frags
  const int m = lane & 15;
  const int quad = lane >> 4;
  f32x4 gacc[8];
#pragma unroll
  for (int tt = 0; tt < 8; ++tt) gacc[tt] = (f32x4){0.f, 0.f, 0.f, 0.f};
#pragma unroll
  for (int sk = 0; sk < 4; ++sk) {
    BF8 a;
    a.q = *(const uint4*)&tile[wrow0 + m][sk * 32 + quad * 8];
#pragma unroll
    for (int tt = 0; tt < 8; ++tt) {
      BF8 b;
      b.q = *(const uint4*)(wpack2 + (size_t)((tt * 4 + sk) * 64 + lane) * 8);
      gacc[tt] = __builtin_amdgcn_mfma_f32_16x16x32_bf16(a.v, b.v, gacc[tt], 0, 0, 0);
    }
  }

  float sc[4];
#pragma unroll
  for (int r = 0; r < 4; ++r) {
    const int lr = wrow0 + quad * 4 + r;
    int rr = nbase + lr;
    rr = rr < N ? rr : N - 1;
    const float mm = mask[rr];
    const float S_all = sAll[lr];
    const float S_rel = sRel[lr];
    const float s2 = mm * mm * S_all;
    const float nrm = sqrtf(s2);
    const float ncl = fminf(fmaxf(nrm, EPS), MAX_TANH_ARG);
    const float f1 = tanhf(ncl) / fmaxf(nrm, EPS) * mm * mm * mm;  // x1 = f1*relu(c1)
    const float r2 = f1 * f1 * S_rel;
    const float nr = sqrtf(r2);
    const float nc2 = fminf(fmaxf(nr, EPS), 1.0f - PROJ_EPS);
    const float ls = 0.5f * logf((1.f + nc2) / (1.f - nc2)) / fmaxf(nr, EPS);
    sc[r] = ls * mm * mm * f1;
  }
#pragma unroll
  for (int tt = 0; tt < 8; ++tt) {
    const int c = tt * 16 + m;
#pragma unroll
    for (int r = 0; r < 4; ++r)
      tile[wrow0 + quad * 4 + r][c] = f2bf(gacc[tt][r] * sc[r]);
  }
  const int r16 = lane >> 2;
  const int sub2 = lane & 3;
  const int grow = nbase + wrow0 + r16;
  if (grow < N) {
#pragma unroll
    for (int p = 0; p < 4; ++p) {
      *(uint4*)((char*)msg2 + (size_t)p * planeBytes + (size_t)grow * 64 + sub2 * 16) =
          *(const uint4*)((const char*)&tile[wrow0 + r16][0] + p * 64 + sub2 * 16);
    }
  }
}

// ---------------------------------------------------------------------------
// agg_final: fused gather(all 4 planes) + exp-map epilogue, fp32 out.
// All 4 planes' c2 stay in registers (32 floats); full ||c2||^2 via in-quad
// shuffle; out = f2*relu(c2) written directly. Same rotation/pipeline as
// agg_gemm1; no LDS c-tile, no barriers.
// ---------------------------------------------------------------------------
__global__ __launch_bounds__(256, 3) void agg_final_kernel(
    const unsigned short* __restrict__ msg2, const unsigned* __restrict__ edges,
    const float* __restrict__ mask, float* __restrict__ out, int N,
    int planeBytes) {
  __shared__ unsigned ep[64 * 36];
  const int t = threadIdx.x;
  const int lane = t & 63;
  const int wv = t >> 6;
  const int nbase = blockIdx.x * 64;
  const int wrow0 = wv * 16;
  const int pstart = blockIdx.x & 3;

#pragma unroll
  for (int i = 0; i < 2; ++i) {
    const int idx = lane + i * 64;
    const int row = idx >> 3;
    const int qd = idx & 7;
    const int gn = nbase + wrow0 + row;
    uint4 v = {0u, 0u, 0u, 0u};
    if (gn < N) v = *(const uint4*)(edges + (size_t)gn * 32 + qd * 4);
    *(uint4*)&ep[(wrow0 + row) * 36 + qd * 4] = v;
  }

  const int node = lane >> 2;
  const int sub = lane & 3;
  const int suboff = sub * 16;
  const unsigned* mp = ep + (wrow0 + node) * 36;
  unsigned ew[32];
#pragma unroll
  for (int i = 0; i < 8; ++i) *(uint4*)&ew[4 * i] = *(const uint4*)(mp + 4 * i);

  const char* pb[4];
#pragma unroll
  for (int ph = 0; ph < 4; ++ph)
    pb[ph] = (const char*)msg2 + (size_t)((pstart + ph) & 3) * planeBytes;

  f32x2 acc[16];  // [phase][d]
#pragma unroll
  for (int i = 0; i < 16; ++i) acc[i] = (f32x2){0.f, 0.f};

  uint4 q[16];
#pragma unroll
  for (int e = 0; e < 16; ++e)
    q[e] = *(const uint4*)(pb[e >> 5] + ((ew[e & 31] & 0xffffu) * 64 + suboff));

#pragma unroll
  for (int e = 0; e < 128; ++e) {
    const int k = e & 31;
    const int ph = e >> 5;
    const float w = (float)__builtin_bit_cast(_Float16, (unsigned short)(ew[k] >> 16));
    const f32x2 w2 = {w, w};
    const uint4 qq = q[e & 15];
    const int en = e + 16;
    if (en < 128)
      q[e & 15] = *(const uint4*)(pb[en >> 5] + ((ew[en & 31] & 0xffffu) * 64 + suboff));
#pragma unroll
    for (int d = 0; d < 4; ++d) {
      const unsigned qd = (&qq.x)[d];
      f32x2 v2;
      v2.x = __builtin_bit_cast(float, qd << 16);
      v2.y = __builtin_bit_cast(float, qd & 0xffff0000u);
      acc[ph * 4 + d] = __builtin_elementwise_fma(v2, w2, acc[ph * 4 + d]);
    }
  }

  float s_all = 0.f;
#pragma unroll
  for (int i = 0; i < 16; ++i) {
    s_all = fmaf(acc[i].x, acc[i].x, s_all);
    s_all = fmaf(acc[i].y, acc[i].y, s_all);
  }
  s_all += __shfl_xor(s_all, 1);
  s_all += __shfl_xor(s_all, 2);

  const int gnode = nbase + wrow0 + node;
  const int gnc = gnode < N ? gnode : N - 1;
  const float mm = mask[gnc];
  const float s2 = mm * mm * s_all;
  const float nrm = sqrtf(s2);
  const float ncl = fminf(fmaxf(nrm, EPS), MAX_TANH_ARG);
  const float f2 = tanhf(ncl) / fmaxf(nrm, EPS) * mm * mm * mm;

  if (gnode < N) {
    float* orow = out + (size_t)gnode * 128;
#pragma unroll
    for (int ph = 0; ph < 4; ++ph) {
      const int p = (pstart + ph) & 3;
      float4 o0, o1;
      o0.x = f2 * fmaxf(acc[ph * 4 + 0].x, 0.f);
      o0.y = f2 * fmaxf(acc[ph * 4 + 0].y, 0.f);
      o0.z = f2 * fmaxf(acc[ph * 4 + 1].x, 0.f);
      o0.w = f2 * fmaxf(acc[ph * 4 + 1].y, 0.f);
      o1.x = f2 * fmaxf(acc[ph * 4 + 2].x, 0.f);
      o1.y = f2 * fmaxf(acc[ph * 4 + 2].y, 0.f);
      o1.z = f2 * fmaxf(acc[ph * 4 + 3].x, 0.f);
      o1.w = f2 * fmaxf(acc[ph * 4 + 3].y, 0.f);
      *(float4*)(orow + p * 32 + sub * 8) = o0;
      *(float4*)(orow + p * 32 + sub * 8 + 4) = o1;
    }
  }
}

extern "C" void kernel_launch(void* const* d_in, const int* in_sizes, int n_in,
                              void* d_out, int out_size, void* d_ws, size_t ws_size,
                              hipStream_t stream) {
  const float* node = (const float*)d_in[0];        // [N,128] fp32
  const int* adj = (const int*)d_in[1];             // [N,32] int32
  const float* wgt = (const float*)d_in[2];         // [N,32] fp32
  const float* mask = (const float*)d_in[3];        // [N,1] fp32
  const float* mw = (const float*)d_in[4];          // [2,128,128] fp32
  float* out = (float*)d_out;
  const int N = in_sizes[0] / 128;
  const int gb = (N + 63) / 64;
  const int planeBytes = gb * 64 * 64;
  const int nedge = N * 32;

  // d_out scratch: [0,4*pB) msg1 planes — dead before agg_final's out writes.
  // ws: wpack 64 KiB | msg2 planes (4*pB) | edges (4B*nedge).
  unsigned short* msg1 = (unsigned short*)d_out;
  unsigned short* wpack = (unsigned short*)d_ws;
  unsigned short* msg2 = (unsigned short*)((char*)d_ws + 65536);
  unsigned* edges = (unsigned*)((char*)d_ws + 65536 + (size_t)4 * planeBytes);

  hipLaunchKernelGGL(prep_kernel, dim3(16), dim3(256), 0, stream, mw, wpack);
  hipLaunchKernelGGL(gemm0_kernel, dim3(gb), dim3(256), 0, stream,
                     node, mask, wpack, msg1, adj, wgt, edges, nedge, N, planeBytes);
  hipLaunchKernelGGL(agg_gemm1_kernel, dim3(gb), dim3(256), 0, stream,
                     msg1, edges, mask, wpack + 16384, msg2, N, planeBytes);
  hipLaunchKernelGGL(agg_final_kernel, dim3(gb), dim3(256), 0, stream,
                     msg2, edges, mask, out, N, planeBytes);
}

// Round 2
// 225.000 us; speedup vs baseline: 1.7605x; 1.7605x over previous
//
#include <hip/hip_runtime.h>

#define EPS 1e-5f
#define PROJ_EPS 1e-5f
#define MAX_TANH_ARG 15.0f

typedef __bf16 bf16x8 __attribute__((ext_vector_type(8)));
typedef float f32x4 __attribute__((ext_vector_type(4)));
typedef float f32x2 __attribute__((ext_vector_type(2)));

__device__ __forceinline__ unsigned short f2bf(float f) {
  unsigned u = __builtin_bit_cast(unsigned, f);
  u += 0x7fffu + ((u >> 16) & 1u);   // round-to-nearest-even
  return (unsigned short)(u >> 16);
}

union BF8 {
  unsigned short u[8];
  bf16x8 v;
  uint4 q;
};

// ---------------------------------------------------------------------------
// prep: W[layer][k][n] -> bf16 MFMA B-frag order.
// ---------------------------------------------------------------------------
__global__ __launch_bounds__(256) void prep_kernel(
    const float* __restrict__ W, unsigned short* __restrict__ wpack) {
  const int tid = blockIdx.x * 256 + threadIdx.x;
  if (tid >= 4096) return;
  const int l = tid & 63;
  const int s = (tid >> 6) & 3;
  const int tt = (tid >> 8) & 7;
  const int layer = tid >> 11;
  const int q2 = l >> 4;
  const int n = tt * 16 + (l & 15);
  unsigned short* dst = wpack + ((size_t)((layer * 32 + tt * 4 + s) * 64 + l)) * 8;
  const float* src = W + (size_t)layer * 16384;
#pragma unroll
  for (int j = 0; j < 8; ++j) {
    const int k = s * 32 + q2 * 8 + j;
    dst[j] = f2bf(src[(size_t)k * 128 + n]);
  }
}

// ---------------------------------------------------------------------------
// gemm0: msg1 planes = mask^2 * (node_repr @ W0); also packs this tile's
// edges (u16 id | f16 w) -- coalesced, overlapped with the MFMA pipeline.
// No __syncthreads: every wave stages/reads/writes only its own 16 rows.
// ---------------------------------------------------------------------------
__global__ __launch_bounds__(256) void gemm0_kernel(
    const float* __restrict__ xf, const float* __restrict__ mask,
    const unsigned short* __restrict__ wpack, unsigned short* __restrict__ msg,
    const int* __restrict__ adj, const float* __restrict__ wgt,
    unsigned* __restrict__ edges, int nedge, int N, int planeBytes) {
  __shared__ unsigned short tile[64][136];
  const int t = threadIdx.x;
  const int lane = t & 63;
  const int wv = t >> 6;
  const int m = lane & 15;
  const int quad = lane >> 4;
  const int base = blockIdx.x * 64;
  const int wbase = base + wv * 16;

  // Pack this tile's 2048 edges (8 coalesced iterations).
#pragma unroll
  for (int i = 0; i < 8; ++i) {
    const int ge = base * 32 + i * 256 + t;
    if (ge < nedge) {
      const unsigned id = (unsigned)adj[ge] & 0xffffu;
      const unsigned short h = __builtin_bit_cast(unsigned short, (_Float16)wgt[ge]);
      edges[ge] = id | ((unsigned)h << 16);
    }
  }

  {  // coalesced fp32 load -> bf16 stage into own wave's 16 tile rows
    const int r = lane >> 2;
    const int c = (lane & 3) * 32;
    const int gr = wbase + r;
    const int grc = gr < N ? gr : N - 1;
    const float4* src = (const float4*)(xf + (size_t)grc * 128 + c);
    unsigned short* drow = &tile[wv * 16 + r][c];
#pragma unroll
    for (int i = 0; i < 8; ++i) {
      const float4 p = src[i];
      drow[i * 4 + 0] = f2bf(p.x);
      drow[i * 4 + 1] = f2bf(p.y);
      drow[i * 4 + 2] = f2bf(p.z);
      drow[i * 4 + 3] = f2bf(p.w);
    }
  }

  f32x4 acc[8];
#pragma unroll
  for (int tt = 0; tt < 8; ++tt) acc[tt] = (f32x4){0.f, 0.f, 0.f, 0.f};
#pragma unroll
  for (int sk = 0; sk < 4; ++sk) {
    BF8 a;
    a.q = *(const uint4*)&tile[wv * 16 + m][sk * 32 + quad * 8];
#pragma unroll
    for (int tt = 0; tt < 8; ++tt) {
      BF8 b;
      b.q = *(const uint4*)(wpack + (size_t)((tt * 4 + sk) * 64 + lane) * 8);
      acc[tt] = __builtin_amdgcn_mfma_f32_16x16x32_bf16(a.v, b.v, acc[tt], 0, 0, 0);
    }
  }

  float sc[4];
#pragma unroll
  for (int r = 0; r < 4; ++r) {
    int rr = wbase + quad * 4 + r;
    rr = rr < N ? rr : N - 1;
    const float s = mask[rr];
    sc[r] = s * s;
  }
#pragma unroll
  for (int tt = 0; tt < 8; ++tt) {
    const int c = tt * 16 + m;
#pragma unroll
    for (int r = 0; r < 4; ++r)
      tile[wv * 16 + quad * 4 + r][c] = f2bf(acc[tt][r] * sc[r]);
  }
  const int r16 = lane >> 2;
  const int sub2 = lane & 3;
  const int grow = wbase + r16;
  if (grow < N) {
#pragma unroll
    for (int p = 0; p < 4; ++p) {
      *(uint4*)((char*)msg + (size_t)p * planeBytes + (size_t)grow * 64 + sub2 * 16) =
          *(const uint4*)((const char*)&tile[wv * 16 + r16][0] + p * 64 + sub2 * 16);
    }
  }
}

// ---------------------------------------------------------------------------
// agg_gemm1: fused gather(all 4 planes) + gemm1 per 64-node tile.
// Gather uses the PROVEN per-plane pipeline shape (prologue-16 /
// consume+reissue-16 / drain-16, loop-boundary-separated so all 16 q slots
// stay live -> no spill, ~16 loads in flight). Plane order rotated by
// blockIdx&3 (~XCD id&3) to keep per-XCD L2 on one 3.2MB plane at a time.
// Zero __syncthreads: wave w gathers rows [w*16,w*16+16) and feeds exactly
// those rows to its own MFMAs.
// ---------------------------------------------------------------------------
__global__ __launch_bounds__(256, 3) void agg_gemm1_kernel(
    const unsigned short* __restrict__ msg, const unsigned* __restrict__ edges,
    const float* __restrict__ mask, const unsigned short* __restrict__ wpack2,
    unsigned short* __restrict__ msg2, int N, int planeBytes) {
  __shared__ unsigned short tile[64][136];
  __shared__ float sAll[64];
  __shared__ float sRel[64];
  const int t = threadIdx.x;
  const int lane = t & 63;
  const int wv = t >> 6;
  const int nbase = blockIdx.x * 64;
  const int wrow0 = wv * 16;
  const int pstart = blockIdx.x & 3;

  const int node = lane >> 2;
  const int sub = lane & 3;
  const int suboff = sub * 16;
  const int gn0 = nbase + wrow0 + node;
  const int gnc = gn0 < N ? gn0 : N - 1;

  // own-node edge words straight from global (row is 128B, 4 threads share)
  unsigned ew[32];
#pragma unroll
  for (int i = 0; i < 8; ++i)
    *(uint4*)&ew[4 * i] = *(const uint4*)(edges + (size_t)gnc * 32 + i * 4);

  float s_all = 0.f, s_rel = 0.f;

#pragma unroll
  for (int phse = 0; phse < 4; ++phse) {
    const int p = (pstart + phse) & 3;
    const char* plane = (const char*)msg + (size_t)p * planeBytes;

    f32x2 acc[4];
#pragma unroll
    for (int d = 0; d < 4; ++d) acc[d] = (f32x2){0.f, 0.f};

    uint4 q[16];
#pragma unroll
    for (int k = 0; k < 16; ++k)
      q[k] = *(const uint4*)(plane + ((size_t)(ew[k] & 0xffffu) * 64 + suboff));

    // consume k, immediately reissue slot k for edge k+16
#pragma unroll
    for (int k = 0; k < 16; ++k) {
      const float w = (float)__builtin_bit_cast(_Float16, (unsigned short)(ew[k] >> 16));
      const f32x2 w2 = {w, w};
      const uint4 qq = q[k];
      q[k] = *(const uint4*)(plane + ((size_t)(ew[16 + k] & 0xffffu) * 64 + suboff));
#pragma unroll
      for (int d = 0; d < 4; ++d) {
        const unsigned qd = (&qq.x)[d];
        f32x2 v2;
        v2.x = __builtin_bit_cast(float, qd << 16);
        v2.y = __builtin_bit_cast(float, qd & 0xffff0000u);
        acc[d] = __builtin_elementwise_fma(v2, w2, acc[d]);
      }
    }
    // drain
#pragma unroll
    for (int k = 0; k < 16; ++k) {
      const float w = (float)__builtin_bit_cast(_Float16,
                                                (unsigned short)(ew[16 + k] >> 16));
      const f32x2 w2 = {w, w};
#pragma unroll
      for (int d = 0; d < 4; ++d) {
        const unsigned qd = (&q[k].x)[d];
        f32x2 v2;
        v2.x = __builtin_bit_cast(float, qd << 16);
        v2.y = __builtin_bit_cast(float, qd & 0xffff0000u);
        acc[d] = __builtin_elementwise_fma(v2, w2, acc[d]);
      }
    }

    // plane epilogue: norms + relu + bf16 pack into own-wave A-tile rows
    uint4 pk4;
    unsigned* pw = &pk4.x;
#pragma unroll
    for (int d = 0; d < 4; ++d) {
      s_all = fmaf(acc[d].x, acc[d].x, s_all);
      s_all = fmaf(acc[d].y, acc[d].y, s_all);
      const float r0 = fmaxf(acc[d].x, 0.f);
      const float r1 = fmaxf(acc[d].y, 0.f);
      s_rel = fmaf(r0, r0, s_rel);
      s_rel = fmaf(r1, r1, s_rel);
      pw[d] = (unsigned)f2bf(r0) | ((unsigned)f2bf(r1) << 16);
    }
    *(uint4*)&tile[wrow0 + node][p * 32 + sub * 8] = pk4;
  }

  s_all += __shfl_xor(s_all, 1);
  s_all += __shfl_xor(s_all, 2);
  s_rel += __shfl_xor(s_rel, 1);
  s_rel += __shfl_xor(s_rel, 2);
  if (sub == 0) {
    sAll[wrow0 + node] = s_all;
    sRel[wrow0 + node] = s_rel;
  }

  // gemm phase: A = relu(c1) bf16 from own-wave LDS rows, B = W1 frags
  const int m = lane & 15;
  const int quad = lane >> 4;
  f32x4 gacc[8];
#pragma unroll
  for (int tt = 0; tt < 8; ++tt) gacc[tt] = (f32x4){0.f, 0.f, 0.f, 0.f};
#pragma unroll
  for (int sk = 0; sk < 4; ++sk) {
    BF8 a;
    a.q = *(const uint4*)&tile[wrow0 + m][sk * 32 + quad * 8];
#pragma unroll
    for (int tt = 0; tt < 8; ++tt) {
      BF8 b;
      b.q = *(const uint4*)(wpack2 + (size_t)((tt * 4 + sk) * 64 + lane) * 8);
      gacc[tt] = __builtin_amdgcn_mfma_f32_16x16x32_bf16(a.v, b.v, gacc[tt], 0, 0, 0);
    }
  }

  float sc[4];
#pragma unroll
  for (int r = 0; r < 4; ++r) {
    const int lr = wrow0 + quad * 4 + r;
    int rr = nbase + lr;
    rr = rr < N ? rr : N - 1;
    const float mm = mask[rr];
    const float S_all = sAll[lr];
    const float S_rel = sRel[lr];
    const float s2 = mm * mm * S_all;
    const float nrm = sqrtf(s2);
    const float ncl = fminf(fmaxf(nrm, EPS), MAX_TANH_ARG);
    const float f1 = tanhf(ncl) / fmaxf(nrm, EPS) * mm * mm * mm;  // x1 = f1*relu(c1)
    const float r2 = f1 * f1 * S_rel;
    const float nr = sqrtf(r2);
    const float nc2 = fminf(fmaxf(nr, EPS), 1.0f - PROJ_EPS);
    const float ls = 0.5f * logf((1.f + nc2) / (1.f - nc2)) / fmaxf(nr, EPS);
    sc[r] = ls * mm * mm * f1;
  }
#pragma unroll
  for (int tt = 0; tt < 8; ++tt) {
    const int c = tt * 16 + m;
#pragma unroll
    for (int r = 0; r < 4; ++r)
      tile[wrow0 + quad * 4 + r][c] = f2bf(gacc[tt][r] * sc[r]);
  }
  const int r16 = lane >> 2;
  const int sub2 = lane & 3;
  const int grow = nbase + wrow0 + r16;
  if (grow < N) {
#pragma unroll
    for (int p = 0; p < 4; ++p) {
      *(uint4*)((char*)msg2 + (size_t)p * planeBytes + (size_t)grow * 64 + sub2 * 16) =
          *(const uint4*)((const char*)&tile[wrow0 + r16][0] + p * 64 + sub2 * 16);
    }
  }
}

// ---------------------------------------------------------------------------
// agg_final: fused gather(all 4 planes) + exp-map epilogue, fp32 out.
// Same proven per-plane pipeline; per-plane results kept in res[16] f32x2.
// No LDS, no barriers.
// ---------------------------------------------------------------------------
__global__ __launch_bounds__(256, 3) void agg_final_kernel(
    const unsigned short* __restrict__ msg2, const unsigned* __restrict__ edges,
    const float* __restrict__ mask, float* __restrict__ out, int N,
    int planeBytes) {
  const int t = threadIdx.x;
  const int lane = t & 63;
  const int wv = t >> 6;
  const int nbase = blockIdx.x * 64;
  const int wrow0 = wv * 16;
  const int pstart = blockIdx.x & 3;

  const int node = lane >> 2;
  const int sub = lane & 3;
  const int suboff = sub * 16;
  const int gnode = nbase + wrow0 + node;
  const int gnc = gnode < N ? gnode : N - 1;

  unsigned ew[32];
#pragma unroll
  for (int i = 0; i < 8; ++i)
    *(uint4*)&ew[4 * i] = *(const uint4*)(edges + (size_t)gnc * 32 + i * 4);

  f32x2 res[16];  // [phase][d]

#pragma unroll
  for (int phse = 0; phse < 4; ++phse) {
    const int p = (pstart + phse) & 3;
    const char* plane = (const char*)msg2 + (size_t)p * planeBytes;

    f32x2 acc[4];
#pragma unroll
    for (int d = 0; d < 4; ++d) acc[d] = (f32x2){0.f, 0.f};

    uint4 q[16];
#pragma unroll
    for (int k = 0; k < 16; ++k)
      q[k] = *(const uint4*)(plane + ((size_t)(ew[k] & 0xffffu) * 64 + suboff));

#pragma unroll
    for (int k = 0; k < 16; ++k) {
      const float w = (float)__builtin_bit_cast(_Float16, (unsigned short)(ew[k] >> 16));
      const f32x2 w2 = {w, w};
      const uint4 qq = q[k];
      q[k] = *(const uint4*)(plane + ((size_t)(ew[16 + k] & 0xffffu) * 64 + suboff));
#pragma unroll
      for (int d = 0; d < 4; ++d) {
        const unsigned qd = (&qq.x)[d];
        f32x2 v2;
        v2.x = __builtin_bit_cast(float, qd << 16);
        v2.y = __builtin_bit_cast(float, qd & 0xffff0000u);
        acc[d] = __builtin_elementwise_fma(v2, w2, acc[d]);
      }
    }
#pragma unroll
    for (int k = 0; k < 16; ++k) {
      const float w = (float)__builtin_bit_cast(_Float16,
                                                (unsigned short)(ew[16 + k] >> 16));
      const f32x2 w2 = {w, w};
#pragma unroll
      for (int d = 0; d < 4; ++d) {
        const unsigned qd = (&q[k].x)[d];
        f32x2 v2;
        v2.x = __builtin_bit_cast(float, qd << 16);
        v2.y = __builtin_bit_cast(float, qd & 0xffff0000u);
        acc[d] = __builtin_elementwise_fma(v2, w2, acc[d]);
      }
    }
#pragma unroll
    for (int d = 0; d < 4; ++d) res[phse * 4 + d] = acc[d];
  }

  float s_all = 0.f;
#pragma unroll
  for (int i = 0; i < 16; ++i) {
    s_all = fmaf(res[i].x, res[i].x, s_all);
    s_all = fmaf(res[i].y, res[i].y, s_all);
  }
  s_all += __shfl_xor(s_all, 1);
  s_all += __shfl_xor(s_all, 2);

  const float mm = mask[gnc];
  const float s2 = mm * mm * s_all;
  const float nrm = sqrtf(s2);
  const float ncl = fminf(fmaxf(nrm, EPS), MAX_TANH_ARG);
  const float f2 = tanhf(ncl) / fmaxf(nrm, EPS) * mm * mm * mm;

  if (gnode < N) {
    float* orow = out + (size_t)gnode * 128;
#pragma unroll
    for (int phse = 0; phse < 4; ++phse) {
      const int p = (pstart + phse) & 3;
      float4 o0, o1;
      o0.x = f2 * fmaxf(res[phse * 4 + 0].x, 0.f);
      o0.y = f2 * fmaxf(res[phse * 4 + 0].y, 0.f);
      o0.z = f2 * fmaxf(res[phse * 4 + 1].x, 0.f);
      o0.w = f2 * fmaxf(res[phse * 4 + 1].y, 0.f);
      o1.x = f2 * fmaxf(res[phse * 4 + 2].x, 0.f);
      o1.y = f2 * fmaxf(res[phse * 4 + 2].y, 0.f);
      o1.z = f2 * fmaxf(res[phse * 4 + 3].x, 0.f);
      o1.w = f2 * fmaxf(res[phse * 4 + 3].y, 0.f);
      *(float4*)(orow + p * 32 + sub * 8) = o0;
      *(float4*)(orow + p * 32 + sub * 8 + 4) = o1;
    }
  }
}

extern "C" void kernel_launch(void* const* d_in, const int* in_sizes, int n_in,
                              void* d_out, int out_size, void* d_ws, size_t ws_size,
                              hipStream_t stream) {
  const float* node = (const float*)d_in[0];        // [N,128] fp32
  const int* adj = (const int*)d_in[1];             // [N,32] int32
  const float* wgt = (const float*)d_in[2];         // [N,32] fp32
  const float* mask = (const float*)d_in[3];        // [N,1] fp32
  const float* mw = (const float*)d_in[4];          // [2,128,128] fp32
  float* out = (float*)d_out;
  const int N = in_sizes[0] / 128;
  const int gb = (N + 63) / 64;
  const int planeBytes = gb * 64 * 64;
  const int nedge = N * 32;

  // d_out scratch: [0,4*pB) msg1 planes — dead before agg_final's out writes.
  // ws: wpack 64 KiB | msg2 planes (4*pB) | edges (4B*nedge).
  unsigned short* msg1 = (unsigned short*)d_out;
  unsigned short* wpack = (unsigned short*)d_ws;
  unsigned short* msg2 = (unsigned short*)((char*)d_ws + 65536);
  unsigned* edges = (unsigned*)((char*)d_ws + 65536 + (size_t)4 * planeBytes);

  hipLaunchKernelGGL(prep_kernel, dim3(16), dim3(256), 0, stream, mw, wpack);
  hipLaunchKernelGGL(gemm0_kernel, dim3(gb), dim3(256), 0, stream,
                     node, mask, wpack, msg1, adj, wgt, edges, nedge, N, planeBytes);
  hipLaunchKernelGGL(agg_gemm1_kernel, dim3(gb), dim3(256), 0, stream,
                     msg1, edges, mask, wpack + 16384, msg2, N, planeBytes);
  hipLaunchKernelGGL(agg_final_kernel, dim3(gb), dim3(256), 0, stream,
                     msg2, edges, mask, out, N, planeBytes);
}